// Round 1
// baseline (614.984 us; speedup 1.0000x reference)
//
#include <hip/hip_runtime.h>
#include <math.h>

#define N_PTS 50000
#define KNN_K 16

using bf16x8 = __attribute__((ext_vector_type(8))) __bf16;
using f32x4  = __attribute__((ext_vector_type(4))) float;

// ---------------------------------------------------------------------------
// Kernel 1: per-point features p0 = xyz@W1+b1, p1 = p0@W2+b2   (fp32, tiny)
// ---------------------------------------------------------------------------
__global__ __launch_bounds__(256) void k1_pfeat(
    const float* __restrict__ xyz, const float* __restrict__ W1,
    const float* __restrict__ b1,  const float* __restrict__ W2,
    const float* __restrict__ b2,  float* __restrict__ p0g,
    float* __restrict__ p1g)
{
    int i = blockIdx.x * 256 + threadIdx.x;
    if (i >= N_PTS) return;
    float x = xyz[3*i+0], y = xyz[3*i+1], z = xyz[3*i+2];
    float v[64];
    #pragma unroll
    for (int c = 0; c < 64; ++c)
        v[c] = b1[c] + x*W1[c] + y*W1[64+c] + z*W1[128+c];
    #pragma unroll 8
    for (int c = 0; c < 64; ++c) p0g[(size_t)i*64 + c] = v[c];
    for (int c = 0; c < 64; ++c) {
        float a = b2[c];
        #pragma unroll
        for (int k = 0; k < 64; ++k) a += v[k] * W2[k*64 + c];
        p1g[(size_t)i*64 + c] = a;
    }
}

// ---------------------------------------------------------------------------
// Kernel 2: p_local[n][c] = max_k p0[knn[n][k]][c] - p0[n][c]
// ---------------------------------------------------------------------------
__global__ __launch_bounds__(256) void k2_plocal(
    const float* __restrict__ p0g, const int* __restrict__ knn,
    float* __restrict__ plg)
{
    int gid = blockIdx.x * 256 + threadIdx.x;
    int n = gid >> 6, c = gid & 63;
    float center = p0g[(size_t)n*64 + c];
    float m = -1e30f;
    #pragma unroll
    for (int k = 0; k < KNN_K; ++k) {
        int j = knn[n*KNN_K + k];
        m = fmaxf(m, p0g[(size_t)j*64 + c]);
    }
    plg[(size_t)n*64 + c] = m - center;
}

// ---------------------------------------------------------------------------
// Kernel 3: repack W3a/W3b (fp32 [128][128], k-major) into bf16 MFMA
// B-fragment order: wf[(t*4+s)*512 + lane*8 + j] = W[k=s*32+(lane>>4)*8+j][c=t*16+(lane&15)]
// so k4 reads each b-fragment as one coalesced dwordx4 at ((t*4+s)*64+lane)*16B.
// ---------------------------------------------------------------------------
__global__ __launch_bounds__(256) void k3_wfrag(
    const float* __restrict__ W3a, const float* __restrict__ W3b,
    __bf16* __restrict__ wfA, __bf16* __restrict__ wfB)
{
    int ci = blockIdx.x * 256 + threadIdx.x;   // 0..2047 chunk id
    if (ci >= 2048) return;
    int t = ci >> 8, s = (ci >> 6) & 3, l = ci & 63;
    int k0 = s*32 + (l >> 4)*8;
    int c  = t*16 + (l & 15);
    #pragma unroll
    for (int j = 0; j < 8; ++j) {
        wfA[ci*8 + j] = (__bf16)W3a[(k0 + j)*128 + c];
        wfB[ci*8 + j] = (__bf16)W3b[(k0 + j)*128 + c];
    }
}

// ---------------------------------------------------------------------------
// Kernel 4: fused edge MLP.  One wave = one point n = 16 edge rows.
// feat[row=kk][0:64]  = p1[knn[n][kk]] - p1[n]
// feat[row=kk][64:128]= p_local[n]
// h = gelu(feat @ W3a + b3a);  out = h @ W3b + b3b
// A-frag: A[m=lane&15][k=quad*8+j]; B-frag: B[k=quad*8+j][n=lane&15];
// C/D: row=quad*4+reg, col=lane&15  (all measured layouts for 16x16x32 bf16).
// h round-trips through a per-wave-private LDS tile (C-layout -> A-layout),
// so no __syncthreads is needed anywhere.
// ---------------------------------------------------------------------------
__global__ __launch_bounds__(512) void k4_mlp(
    const float* __restrict__ p1g, const float* __restrict__ plg,
    const int* __restrict__ knn,
    const __bf16* __restrict__ wfA, const __bf16* __restrict__ wfB,
    const float* __restrict__ b3a, const float* __restrict__ b3b,
    float* __restrict__ out)
{
    // 16 rows x 136 bf16 stride per wave (136*2=272B rows keep 16B alignment,
    // pad breaks the power-of-2 bank stride). 8 waves * 4352B = 34.8 KB.
    __shared__ __align__(16) __bf16 lds_h[8][16*136];

    const int tid  = threadIdx.x;
    const int wave = tid >> 6;
    const int lane = tid & 63;
    const int lrow = lane & 15;   // row within wave tile == neighbor slot kk
    const int quad = lane >> 4;   // 0..3

    const int n = blockIdx.x * 8 + wave;          // point index (exact: 6250*8)
    const int j = knn[n*KNN_K + lrow];            // this row's neighbor

    // ---- build A fragments for matmul1 (4 k-steps of 32) -------------------
    bf16x8 afrag[4];
    {
        const float* pj = p1g + (size_t)j*64;
        const float* pn = p1g + (size_t)n*64;
        const float* pl = plg + (size_t)n*64;
        #pragma unroll
        for (int s = 0; s < 2; ++s) {
            int o = s*32 + quad*8;
            float4 a0 = *(const float4*)(pj + o);
            float4 a1 = *(const float4*)(pj + o + 4);
            float4 c0 = *(const float4*)(pn + o);
            float4 c1 = *(const float4*)(pn + o + 4);
            bf16x8 f;
            f[0] = (__bf16)(a0.x - c0.x); f[1] = (__bf16)(a0.y - c0.y);
            f[2] = (__bf16)(a0.z - c0.z); f[3] = (__bf16)(a0.w - c0.w);
            f[4] = (__bf16)(a1.x - c1.x); f[5] = (__bf16)(a1.y - c1.y);
            f[6] = (__bf16)(a1.z - c1.z); f[7] = (__bf16)(a1.w - c1.w);
            afrag[s] = f;
        }
        #pragma unroll
        for (int s = 0; s < 2; ++s) {
            int o = s*32 + quad*8;
            float4 a0 = *(const float4*)(pl + o);
            float4 a1 = *(const float4*)(pl + o + 4);
            bf16x8 f;
            f[0] = (__bf16)a0.x; f[1] = (__bf16)a0.y;
            f[2] = (__bf16)a0.z; f[3] = (__bf16)a0.w;
            f[4] = (__bf16)a1.x; f[5] = (__bf16)a1.y;
            f[6] = (__bf16)a1.z; f[7] = (__bf16)a1.w;
            afrag[2+s] = f;
        }
    }

    // ---- matmul1: h_pre = feat @ W3a + b3a ---------------------------------
    f32x4 acc[8];
    #pragma unroll
    for (int t = 0; t < 8; ++t) {
        float bv = b3a[t*16 + lrow];
        f32x4 a = {bv, bv, bv, bv};
        acc[t] = a;
    }
    #pragma unroll
    for (int s = 0; s < 4; ++s) {
        #pragma unroll
        for (int t = 0; t < 8; ++t) {
            bf16x8 b = *(const bf16x8*)(wfA + (((t*4 + s)*64 + lane) << 3));
            acc[t] = __builtin_amdgcn_mfma_f32_16x16x32_bf16(afrag[s], b, acc[t], 0, 0, 0);
        }
    }

    // ---- exact gelu, C-layout -> LDS (bf16) --------------------------------
    __bf16* hb = &lds_h[wave][0];
    #pragma unroll
    for (int t = 0; t < 8; ++t) {
        #pragma unroll
        for (int i = 0; i < 4; ++i) {
            float x = acc[t][i];
            float g = 0.5f * x * (1.0f + erff(x * 0.7071067811865475f));
            hb[(quad*4 + i)*136 + t*16 + lrow] = (__bf16)g;
        }
    }

    // ---- matmul2: out = h @ W3b + b3b --------------------------------------
    f32x4 acc2[8];
    #pragma unroll
    for (int t = 0; t < 8; ++t) {
        float bv = b3b[t*16 + lrow];
        f32x4 a = {bv, bv, bv, bv};
        acc2[t] = a;
    }
    #pragma unroll
    for (int s = 0; s < 4; ++s) {
        bf16x8 a = *(const bf16x8*)(hb + lrow*136 + s*32 + quad*8);
        #pragma unroll
        for (int t = 0; t < 8; ++t) {
            bf16x8 b = *(const bf16x8*)(wfB + (((t*4 + s)*64 + lane) << 3));
            acc2[t] = __builtin_amdgcn_mfma_f32_16x16x32_bf16(a, b, acc2[t], 0, 0, 0);
        }
    }

    // ---- store (coalesced 64B segments per quad) ---------------------------
    float* orow = out + (size_t)n * (KNN_K * 128);
    #pragma unroll
    for (int t = 0; t < 8; ++t) {
        #pragma unroll
        for (int i = 0; i < 4; ++i) {
            orow[(quad*4 + i)*128 + t*16 + lrow] = acc2[t][i];
        }
    }
}

// ---------------------------------------------------------------------------
extern "C" void kernel_launch(void* const* d_in, const int* in_sizes, int n_in,
                              void* d_out, int out_size, void* d_ws, size_t ws_size,
                              hipStream_t stream)
{
    const float* xyz = (const float*)d_in[0];
    const int*   knn = (const int*)  d_in[1];
    const float* W1  = (const float*)d_in[2];
    const float* b1  = (const float*)d_in[3];
    const float* W2  = (const float*)d_in[4];
    const float* b2  = (const float*)d_in[5];
    const float* W3a = (const float*)d_in[6];
    const float* b3a = (const float*)d_in[7];
    const float* W3b = (const float*)d_in[8];
    const float* b3b = (const float*)d_in[9];
    float* out = (float*)d_out;

    // workspace layout (all rewritten every call; ~36.7 MB total)
    float*  p0g = (float*)d_ws;
    float*  p1g = p0g + (size_t)N_PTS * 64;
    float*  plg = p1g + (size_t)N_PTS * 64;
    __bf16* wfA = (__bf16*)(plg + (size_t)N_PTS * 64);
    __bf16* wfB = wfA + 128 * 128;

    hipLaunchKernelGGL(k3_wfrag, dim3(8), dim3(256), 0, stream, W3a, W3b, wfA, wfB);
    hipLaunchKernelGGL(k1_pfeat, dim3((N_PTS + 255) / 256), dim3(256), 0, stream,
                       xyz, W1, b1, W2, b2, p0g, p1g);
    hipLaunchKernelGGL(k2_plocal, dim3(N_PTS * 64 / 256), dim3(256), 0, stream,
                       p0g, knn, plg);
    hipLaunchKernelGGL(k4_mlp, dim3(N_PTS / 8), dim3(512), 0, stream,
                       p1g, plg, knn, wfA, wfB, b3a, b3b, out);
}